// Round 14
// baseline (404.634 us; speedup 1.0000x reference)
//
#include <hip/hip_runtime.h>

typedef long long i64;
typedef __attribute__((ext_vector_type(4))) float f32x4;
typedef __attribute__((ext_vector_type(8))) __bf16 bf16x8;
typedef __attribute__((ext_vector_type(8))) ushort u16x8;

#define FULL 512
#define NBC  24   // B*C = 8*3

__device__ __forceinline__ void gload_lds16(const void* g, void* l) {
  __builtin_amdgcn_global_load_lds(
      (const __attribute__((address_space(1))) void*)g,
      (__attribute__((address_space(3))) void*)l, 16, 0, 0);
}

__device__ __forceinline__ ushort f32_to_bf16_rtn(float x) {
  unsigned u = __float_as_uint(x);
  return (ushort)((u + 0x7FFFu + ((u >> 16) & 1u)) >> 16);
}

// ---------------------------------------------------------------- prep_all: fused preprocessing
__global__ __launch_bounds__(256) void prep_all(
    const float* __restrict__ Wli, const float* __restrict__ Wlt,
    const float* __restrict__ Wlir, const float* __restrict__ Wlo,
    const float* __restrict__ Wk, const float* __restrict__ Wki,
    const float* __restrict__ Wp, const float* __restrict__ Wv,
    const float* __restrict__ blo, const float* __restrict__ bp, const float* __restrict__ bv,
    const float4* __restrict__ ia, const float4* __restrict__ ib, const float4* __restrict__ ic,
    ushort* __restrict__ wreg, float* __restrict__ bpN, float* __restrict__ bvN,
    ushort4* __restrict__ xh, ushort4* __restrict__ xl,
    ushort4* __restrict__ th, ushort4* __restrict__ tl,
    ushort4* __restrict__ rh, ushort4* __restrict__ rl, int n4) {
  __shared__ __align__(16) char smem[34048];
  const i64 WPL = 262144;
  int id = blockIdx.x, tid = threadIdx.x;

  if (id < 384) {
    const float* I; ushort* outH; int inLD, r0, c0;
    if (id < 256) {
      int w = id >> 6, b6 = id & 63;
      r0 = (b6 >> 3) * 64; c0 = (b6 & 7) * 64; inLD = 512;
      const float* ins[4] = {Wli, Wlt, Wlir, Wlo};
      I = ins[w];
      outH = wreg + (i64)(2 * w) * WPL;
    } else {
      int q = id - 256;
      int z = q >> 3, y = q & 7;
      int w = z >> 3, b = z & 7;
      r0 = y * 64; c0 = 0; inLD = 64;
      I = (w ? Wki : Wk) + (i64)b * 512 * 64;
      outH = wreg + (i64)(2 * (4 + w)) * WPL + (i64)b * 64 * 512;
    }
    ushort* outL = outH + WPL;
    ushort (*sH)[68] = (ushort(*)[68])smem;
    ushort (*sL)[68] = (ushort(*)[68])(smem + 64 * 68 * 2);
    int tx = tid & 15, ty = tid >> 4;
    #pragma unroll
    for (int it = 0; it < 4; ++it) {
      int r = it * 16 + ty;
      float4 v = *(const float4*)&I[(i64)(r0 + r) * inLD + c0 + tx * 4];
      float vs[4] = {v.x, v.y, v.z, v.w};
      #pragma unroll
      for (int k = 0; k < 4; ++k) {
        ushort hh = f32_to_bf16_rtn(vs[k]);
        sH[tx * 4 + k][r] = hh;
        sL[tx * 4 + k][r] = f32_to_bf16_rtn(vs[k] - __uint_as_float((unsigned)hh << 16));
      }
    }
    __syncthreads();
    #pragma unroll
    for (int it = 0; it < 4; ++it) {
      int c = it * 16 + ty;
      ushort4 hv, lv;
      ushort* hp = (ushort*)&hv; ushort* lp = (ushort*)&lv;
      #pragma unroll
      for (int k = 0; k < 4; ++k) { hp[k] = sH[c][tx * 4 + k]; lp[k] = sL[c][tx * 4 + k]; }
      i64 off = (i64)(c0 + c) * 512 + r0 + tx * 4;
      *(ushort4*)&outH[off] = hv;
      *(ushort4*)&outL[off] = lv;
    }
  } else if (id < 512) {
    int q = id - 384;
    int sel = q >> 6, b6 = q & 63;
    const float* Wf = sel ? Wv : Wp;
    ushort* oH = wreg + (i64)(12 + 2 * sel) * WPL;
    ushort* oL = oH + WPL;
    int n0 = (b6 >> 3) * 64, k0 = (b6 & 7) * 64;
    int h = n0 >> 6;
    float (*sL)[65] = (float(*)[65])smem;
    float (*sF)[68] = (float(*)[68])(smem + 64 * 65 * 4);
    int tx = tid & 15, ty = tid >> 4;
    float acc[4][4] = {};
    for (int c0 = 0; c0 < 512; c0 += 64) {
      __syncthreads();
      #pragma unroll
      for (int it = 0; it < 4; ++it) {
        int idx = tid + it * 256;
        int r = idx >> 4, c4 = idx & 15;
        float4 v = *(const float4*)&Wlo[(i64)(k0 + r) * 512 + c0 + c4 * 4];
        sL[c4 * 4 + 0][r] = v.x; sL[c4 * 4 + 1][r] = v.y;
        sL[c4 * 4 + 2][r] = v.z; sL[c4 * 4 + 3][r] = v.w;
        float4 w = *(const float4*)&Wf[(i64)h * 32768 + (i64)(c0 + r) * 64 + c4 * 4];
        *(float4*)&sF[r][c4 * 4] = w;
      }
      __syncthreads();
      for (int c = 0; c < 64; ++c) {
        float fv[4], lv[4];
        #pragma unroll
        for (int i = 0; i < 4; ++i) fv[i] = sF[c][ty * 4 + i];
        #pragma unroll
        for (int j = 0; j < 4; ++j) lv[j] = sL[c][tx * 4 + j];
        #pragma unroll
        for (int i = 0; i < 4; ++i)
          #pragma unroll
          for (int j = 0; j < 4; ++j)
            acc[i][j] += fv[i] * lv[j];
      }
    }
    #pragma unroll
    for (int i = 0; i < 4; ++i)
      #pragma unroll
      for (int j = 0; j < 4; ++j) {
        float v = acc[i][j];
        i64 o = (i64)(n0 + ty * 4 + i) * 512 + k0 + tx * 4 + j;
        ushort hh = f32_to_bf16_rtn(v);
        oH[o] = hh;
        oL[o] = f32_to_bf16_rtn(v - __uint_as_float((unsigned)hh << 16));
      }
  } else if (id < 528) {
    int bidx = id - 512;
    int sel = bidx >> 3, h = bidx & 7;
    const float* W = sel ? Wv : Wp;
    int e = tid & 63, cq = tid >> 6;
    float s = 0.f;
    #pragma unroll 4
    for (int ci = 0; ci < 128; ++ci) {
      int c = cq * 128 + ci;
      s += blo[c] * W[(i64)h * 32768 + (i64)c * 64 + e];
    }
    float* red = (float*)smem;
    red[tid] = s;
    __syncthreads();
    if (cq == 0) {
      float v = red[e] + red[64 + e] + red[128 + e] + red[192 + e];
      int m = h * 64 + e;
      if (!sel) bpN[m] = v + bp[m];
      else      bvN[m] = v + bv[m];
    }
  } else {
    int i = (id - 528) * 256 + tid;
    int stride = 2048 * 256;
    for (; i < n4; i += stride) {
      float4 va = ia[i], vb = ib[i], vc = ic[i];
      float xs[4] = {va.x + vb.x + vc.x, va.y + vb.y + vc.y,
                     va.z + vb.z + vc.z, va.w + vb.w + vc.w};
      float bs[4] = {vb.x, vb.y, vb.z, vb.w};
      float cs[4] = {vc.x, vc.y, vc.z, vc.w};
      ushort4 h4, l4;
      ushort* hp = (ushort*)&h4; ushort* lp = (ushort*)&l4;
      #pragma unroll
      for (int k = 0; k < 4; ++k) {
        ushort hh = f32_to_bf16_rtn(xs[k]); hp[k] = hh;
        lp[k] = f32_to_bf16_rtn(xs[k] - __uint_as_float((unsigned)hh << 16));
      }
      xh[i] = h4; xl[i] = l4;
      #pragma unroll
      for (int k = 0; k < 4; ++k) {
        ushort hh = f32_to_bf16_rtn(bs[k]); hp[k] = hh;
        lp[k] = f32_to_bf16_rtn(bs[k] - __uint_as_float((unsigned)hh << 16));
      }
      th[i] = h4; tl[i] = l4;
      #pragma unroll
      for (int k = 0; k < 4; ++k) {
        ushort hh = f32_to_bf16_rtn(cs[k]); hp[k] = hh;
        lp[k] = f32_to_bf16_rtn(cs[k] - __uint_as_float((unsigned)hh << 16));
      }
      rh[i] = h4; rl[i] = l4;
    }
  }
}

// ---------------------------------------------------------------- in-place bf16 transpose
__global__ __launch_bounds__(256) void transposeIP(ushort* __restrict__ hi, ushort* __restrict__ lo,
                                                   i64 batch) {
  int bi = blockIdx.x, bj = blockIdx.y;
  if (bi > bj) return;
  int z = blockIdx.z;
  ushort* buf = ((z & 1) ? lo : hi) + (i64)(z >> 1) * batch;
  __shared__ ushort tA[64][68];
  __shared__ ushort tB[64][68];
  int tid = threadIdx.x, tx = tid & 15, ty = tid >> 4;
  #pragma unroll
  for (int it = 0; it < 4; ++it) {
    int r = it * 16 + ty;
    ushort4 a = *(const ushort4*)&buf[(i64)(bi * 64 + r) * 512 + bj * 64 + tx * 4];
    ushort* ap = (ushort*)&a;
    #pragma unroll
    for (int k = 0; k < 4; ++k) tA[tx * 4 + k][r] = ap[k];
    if (bi != bj) {
      ushort4 b = *(const ushort4*)&buf[(i64)(bj * 64 + r) * 512 + bi * 64 + tx * 4];
      ushort* bp = (ushort*)&b;
      #pragma unroll
      for (int k = 0; k < 4; ++k) tB[tx * 4 + k][r] = bp[k];
    }
  }
  __syncthreads();
  #pragma unroll
  for (int it = 0; it < 4; ++it) {
    int c = it * 16 + ty;
    ushort4 v; ushort* vp = (ushort*)&v;
    #pragma unroll
    for (int k = 0; k < 4; ++k) vp[k] = tA[c][tx * 4 + k];
    *(ushort4*)&buf[(i64)(bj * 64 + c) * 512 + bi * 64 + tx * 4] = v;
    if (bi != bj) {
      #pragma unroll
      for (int k = 0; k < 4; ++k) vp[k] = tB[c][tx * 4 + k];
      *(ushort4*)&buf[(i64)(bi * 64 + c) * 512 + bj * 64 + tx * 4] = v;
    }
  }
}

// ---------------------------------------------------------------- merged split-bf16 MFMA GEMM
// 256x256 tile, 512 threads (8 waves = 2x4), BK=32 dbuf (128KB LDS), 1 barrier/K-step.
// Halves L2 staging per MFMA vs 128^2 (A/B panels re-read 2x not 4x).
struct GDesc {
  const ushort *Ah, *Al, *Bh, *Bl;
  const float* bias;
  float* Cf; ushort* Chi; ushort* Clo;
  i64 aStride, bStride, cStride, biasStride;
  int bMod, transC, split3;
};

__global__ __launch_bounds__(512, 1) void gemm_m(GDesc dA, GDesc dB, int z0) {
  int Zt = (int)gridDim.z;
  int hid = ((int)blockIdx.z * (int)gridDim.y + (int)blockIdx.y) * (int)gridDim.x + (int)blockIdx.x;
  int xcd = hid & 7, slot = hid >> 3;
  int perX = Zt >> 1;                       // blocks per XCD = Zt*4/8
  int G = xcd * perX + slot;
  int zz = G >> 2;
  int idx4 = G & 3;
  int m0 = (idx4 >> 1) * 256, n0 = (idx4 & 1) * 256;

  GDesc d = (zz < z0) ? dA : dB;
  int z = (zz < z0) ? zz : zz - z0;
  const int K = 512, N = 512;
  const ushort* Ah = d.Ah + (i64)z * d.aStride + (i64)m0 * K;
  const ushort* Al = d.Al + (i64)z * d.aStride + (i64)m0 * K;
  const ushort* Bh = d.Bh + (i64)(z % d.bMod) * d.bStride + (i64)n0 * K;
  const ushort* Bl = d.Bl + (i64)(z % d.bMod) * d.bStride + (i64)n0 * K;

  __shared__ ushort lds[65536];   // 128KB: buf b @ b*65536B, plane p @ +p*16384B

  int tid = threadIdx.x;
  int lane = tid & 63, wid = tid >> 6;
  int wr = wid >> 2, wc = wid & 3;          // 2x4 wave grid; wave tile 128x64
  int fr = lane & 15, fg = lane >> 4;

  f32x4 acc[8][4] = {};

  auto STAGE = [&](int t, int b) {
    #pragma unroll
    for (int p = 0; p < 4; ++p) {
      if (!d.split3 && (p == 1 || p == 3)) continue;
      const ushort* gb = (p == 0) ? Ah : (p == 1) ? Al : (p == 2) ? Bh : Bl;
      #pragma unroll
      for (int it = 0; it < 2; ++it) {
        int pos = it * 8192 + tid * 16;
        int r = pos >> 6;                   // 0..255
        int cb = (pos & 63) >> 4;
        int gcb = cb ^ ((r >> 1) & 3);
        const char* g = (const char*)gb + (i64)r * 1024 + t * 64 + gcb * 16;
        char* l = (char*)lds + b * 65536 + p * 16384 + it * 8192 + tid * 16;
        gload_lds16(g, l);
      }
    }
  };

  STAGE(0, 0);

  for (int t = 0; t < 16; ++t) {
    __syncthreads();
    if (t + 1 < 16) STAGE(t + 1, (t + 1) & 1);
    const char* B = (const char*)lds + (t & 1) * 65536;

    bf16x8 aH[8], aL[8];
    #pragma unroll
    for (int i = 0; i < 8; ++i) {
      int row = wr * 128 + i * 16 + fr;
      int off = row * 64 + ((fg ^ ((row >> 1) & 3)) << 4);
      aH[i] = *(const bf16x8*)(B + off);
      if (d.split3) aL[i] = *(const bf16x8*)(B + 16384 + off);
    }
    #pragma unroll
    for (int j = 0; j < 4; ++j) {
      int row = wc * 64 + j * 16 + fr;
      int off = row * 64 + ((fg ^ ((row >> 1) & 3)) << 4);
      bf16x8 bH = *(const bf16x8*)(B + 32768 + off);
      if (d.split3) {
        bf16x8 bL = *(const bf16x8*)(B + 49152 + off);
        #pragma unroll
        for (int i = 0; i < 8; ++i) {
          acc[i][j] = __builtin_amdgcn_mfma_f32_16x16x32_bf16(aH[i], bH, acc[i][j], 0, 0, 0);
          acc[i][j] = __builtin_amdgcn_mfma_f32_16x16x32_bf16(aH[i], bL, acc[i][j], 0, 0, 0);
          acc[i][j] = __builtin_amdgcn_mfma_f32_16x16x32_bf16(aL[i], bH, acc[i][j], 0, 0, 0);
        }
      } else {
        #pragma unroll
        for (int i = 0; i < 8; ++i)
          acc[i][j] = __builtin_amdgcn_mfma_f32_16x16x32_bf16(aH[i], bH, acc[i][j], 0, 0, 0);
      }
    }
  }

  // ---------------- epilogue (per-wave 16KB LDS regions) ----------------
  __syncthreads();
  char* wb = (char*)lds + wid * 16384;

  if (d.Cf) {
    #pragma unroll
    for (int j = 0; j < 4; ++j) {
      int col = n0 + wc * 64 + j * 16 + fr;
      float bv = d.bias ? d.bias[(i64)z * d.biasStride + col] : 0.f;
      #pragma unroll
      for (int i = 0; i < 8; ++i)
        #pragma unroll
        for (int q = 0; q < 4; ++q) {
          int row = m0 + wr * 128 + i * 16 + fg * 4 + q;
          d.Cf[(i64)z * d.cStride + (i64)row * N + col] = acc[i][j][q] + bv;
        }
    }
  } else if (!d.transC) {
    #pragma unroll
    for (int ih = 0; ih < 2; ++ih) {
      #pragma unroll
      for (int j = 0; j < 4; ++j) {
        int coll = j * 16 + fr;
        float bv = d.bias ? d.bias[(i64)z * d.biasStride + n0 + wc * 64 + coll] : 0.f;
        #pragma unroll
        for (int i2 = 0; i2 < 4; ++i2) {
          int i = ih * 4 + i2;
          #pragma unroll
          for (int q = 0; q < 4; ++q) {
            int rowl = i2 * 16 + fg * 4 + q;
            float v = acc[i][j][q] + bv;
            int off = rowl * 128 + ((((coll >> 3) ^ (rowl & 7)) << 4)) + (coll & 7) * 2;
            ushort hh = f32_to_bf16_rtn(v);
            *(ushort*)(wb + off) = hh;
            *(ushort*)(wb + 8192 + off) = f32_to_bf16_rtn(v - __uint_as_float((unsigned)hh << 16));
          }
        }
      }
      #pragma unroll
      for (int rep = 0; rep < 8; ++rep) {
        int rowl = rep * 8 + (lane >> 3), chunk = lane & 7;
        int off = rowl * 128 + ((chunk ^ (rowl & 7)) << 4);
        u16x8 hv = *(const u16x8*)(wb + off);
        u16x8 lv = *(const u16x8*)(wb + 8192 + off);
        i64 gidx = (i64)z * d.cStride + (i64)(m0 + wr * 128 + ih * 64 + rowl) * N +
                   n0 + wc * 64 + chunk * 8;
        *(u16x8*)&d.Chi[gidx] = hv;
        *(u16x8*)&d.Clo[gidx] = lv;
      }
    }
  } else {
    #pragma unroll
    for (int ih = 0; ih < 2; ++ih) {
      #pragma unroll
      for (int j = 0; j < 4; ++j) {
        int coll = j * 16 + fr;
        float bv = d.bias ? d.bias[(i64)z * d.biasStride + n0 + wc * 64 + coll] : 0.f;
        #pragma unroll
        for (int i2 = 0; i2 < 4; ++i2) {
          int i = ih * 4 + i2;
          #pragma unroll
          for (int q = 0; q < 4; ++q) {
            int rowl = i2 * 16 + fg * 4 + q;
            float v = acc[i][j][q] + bv;
            int off = coll * 128 + ((((rowl >> 3) ^ (coll & 7)) << 4)) + (rowl & 7) * 2;
            *(ushort*)(wb + off) = f32_to_bf16_rtn(v);
          }
        }
      }
      #pragma unroll
      for (int rep = 0; rep < 8; ++rep) {
        int colr = rep * 8 + (lane >> 3), chunk = lane & 7;
        int off = colr * 128 + ((chunk ^ (colr & 7)) << 4);
        u16x8 hv = *(const u16x8*)(wb + off);
        i64 gidx = (i64)z * d.cStride + (i64)(n0 + wc * 64 + colr) * N +
                   m0 + wr * 128 + ih * 64 + chunk * 8;
        *(u16x8*)&d.Chi[gidx] = hv;
      }
    }
  }
}

// ---------------------------------------------------------------- mhfuse: mh + fused bias2 + transposeIP(xt)
__global__ __launch_bounds__(256) void mhfuse(
    const float* __restrict__ key, const float* __restrict__ Wpi, float* __restrict__ M,
    const float* __restrict__ bpN, const float* __restrict__ bpi, float* __restrict__ b2,
    ushort* __restrict__ xth, ushort* __restrict__ xtl) {
  __shared__ __align__(16) char smem[34816];
  int id = blockIdx.x, tid = threadIdx.x;

  if (id < 192) {
    float (*sK)[68] = (float(*)[68])smem;
    float (*sW)[68] = (float(*)[68])(smem + 17408);
    int z = id, bc = z >> 3, h = z & 7;
    const float* Kb = key + (i64)bc * FULL * FULL + h * 64;
    const float* Wb = Wpi + (i64)h * FULL * 64;
    float* Mb = M + (i64)z * 64 * 64;

    int tx = tid & 15, ty = tid >> 4;
    float acc[4][4] = {};

    for (int s0 = 0; s0 < FULL; s0 += 64) {
      __syncthreads();
      #pragma unroll
      for (int it = 0; it < 4; ++it) {
        int idx = tid + it * 256;
        int r = idx >> 4, c4 = idx & 15;
        *(float4*)&sK[r][c4 * 4] = *(const float4*)&Kb[(i64)(s0 + r) * FULL + c4 * 4];
        *(float4*)&sW[r][c4 * 4] = *(const float4*)&Wb[(i64)(s0 + r) * 64 + c4 * 4];
      }
      __syncthreads();
      for (int s = 0; s < 64; ++s) {
        float4 a4 = *(const float4*)&sK[s][ty * 4];
        float4 b4 = *(const float4*)&sW[s][tx * 4];
        float av[4] = {a4.x, a4.y, a4.z, a4.w};
        float bv[4] = {b4.x, b4.y, b4.z, b4.w};
        #pragma unroll
        for (int i = 0; i < 4; ++i)
          #pragma unroll
          for (int j = 0; j < 4; ++j)
            acc[i][j] += av[i] * bv[j];
      }
    }
    #pragma unroll
    for (int i = 0; i < 4; ++i)
      #pragma unroll
      for (int j = 0; j < 4; ++j)
        Mb[(ty * 4 + i) * 64 + tx * 4 + j] = acc[i][j];

    __syncthreads();
    float* red = (float*)smem;
    #pragma unroll
    for (int j = 0; j < 4; ++j) {
      float s = 0.f;
      #pragma unroll
      for (int i = 0; i < 4; ++i)
        s += bpN[h * 64 + ty * 4 + i] * acc[i][j];
      red[ty * 68 + tx * 4 + j] = s;
    }
    __syncthreads();
    if (tid < 64) {
      float s = 0.f;
      #pragma unroll
      for (int r = 0; r < 16; ++r) s += red[r * 68 + tid];
      b2[(i64)bc * 512 + h * 64 + tid] = 0.125f * s + bpi[h * 64 + tid];
    }
  } else {
    int id2 = id - 192;
    int z = id2 / 36, t = id2 % 36;
    int bi = 0;
    while (t >= 8 - bi) { t -= 8 - bi; ++bi; }
    int bj = bi + t;
    ushort* buf = ((z & 1) ? xtl : xth) + (i64)(z >> 1) * 262144;
    ushort (*tA)[68] = (ushort(*)[68])smem;
    ushort (*tB)[68] = (ushort(*)[68])(smem + 64 * 68 * 2);
    int tx = tid & 15, ty = tid >> 4;
    #pragma unroll
    for (int it = 0; it < 4; ++it) {
      int r = it * 16 + ty;
      ushort4 a = *(const ushort4*)&buf[(i64)(bi * 64 + r) * 512 + bj * 64 + tx * 4];
      ushort* ap = (ushort*)&a;
      #pragma unroll
      for (int k = 0; k < 4; ++k) tA[tx * 4 + k][r] = ap[k];
      if (bi != bj) {
        ushort4 b = *(const ushort4*)&buf[(i64)(bj * 64 + r) * 512 + bi * 64 + tx * 4];
        ushort* bp = (ushort*)&b;
        #pragma unroll
        for (int k = 0; k < 4; ++k) tB[tx * 4 + k][r] = bp[k];
      }
    }
    __syncthreads();
    #pragma unroll
    for (int it = 0; it < 4; ++it) {
      int c = it * 16 + ty;
      ushort4 v; ushort* vp = (ushort*)&v;
      #pragma unroll
      for (int k = 0; k < 4; ++k) vp[k] = tA[c][tx * 4 + k];
      *(ushort4*)&buf[(i64)(bj * 64 + c) * 512 + bi * 64 + tx * 4] = v;
      if (bi != bj) {
        #pragma unroll
        for (int k = 0; k < 4; ++k) vp[k] = tB[c][tx * 4 + k];
        *(ushort4*)&buf[(i64)(bi * 64 + c) * 512 + bj * 64 + tx * 4] = v;
      }
    }
  }
}

// ---------------------------------------------------------------- WpmT via LWpT planes
__global__ __launch_bounds__(256) void wpm_kernel(
    const float* __restrict__ M, const ushort* __restrict__ WpTh, const ushort* __restrict__ WpTl,
    ushort* __restrict__ outH, ushort* __restrict__ outL) {
  int z = blockIdx.y, h = z & 7;
  int s0 = blockIdx.x * 128;
  __shared__ float sM[64][65];
  __shared__ float sW[64][132];
  int tid = threadIdx.x;
  const float* Mb = M + (i64)z * 4096;
  for (int i = 0; i < 16; ++i) {
    int idx = i * 256 + tid;
    sM[idx >> 6][idx & 63] = Mb[idx];
  }
  for (int i = 0; i < 32; ++i) {
    int idx = i * 256 + tid;
    int e = idx >> 7, s = idx & 127;
    i64 g = (i64)(h * 64 + e) * 512 + s0 + s;
    sW[e][s] = __uint_as_float((unsigned)WpTh[g] << 16) +
               __uint_as_float((unsigned)WpTl[g] << 16);
  }
  __syncthreads();
  i64 obase = (i64)(z >> 3) * ((i64)FULL * FULL) + (i64)(h * 64) * 512 + s0;
  for (int i = 0; i < 32; ++i) {
    int idx = i * 256 + tid;
    int d = idx >> 7, s = idx & 127;
    float a = 0.f;
    #pragma unroll
    for (int e = 0; e < 64; ++e) a += sM[e][d] * sW[e][s];
    float v = 0.125f * a;
    i64 o = obase + (i64)d * 512 + s;
    ushort hh = f32_to_bf16_rtn(v);
    outH[o] = hh;
    outL[o] = f32_to_bf16_rtn(v - __uint_as_float((unsigned)hh << 16));
  }
}

// ---------------------------------------------------------------- MFMA flash attention v5 (r8 proven)
__global__ __launch_bounds__(256, 2) void attn5_kernel(
    const ushort* __restrict__ Qh, const ushort* __restrict__ Ql,
    const ushort* __restrict__ Kh, const ushort* __restrict__ Kl,
    const ushort* __restrict__ Vh, float* __restrict__ out) {
  int z = blockIdx.y;
  int bc = z >> 3, h = z & 7;
  __shared__ __align__(16) char lds[65536];
  int tid = threadIdx.x, lane = tid & 63, wid = tid >> 6;
  int fr = lane & 15, fg = lane >> 4;
  int swz = (fr & 7) << 4;

  const i64 IMG2 = 262144;
  const char* pQh = (const char*)(Qh + (i64)bc * IMG2) + h * 128;
  const char* pQl = (const char*)(Ql + (i64)bc * IMG2) + h * 128;
  const char* bKh = (const char*)(Kh + (i64)bc * IMG2) + h * 128;
  const char* bKl = (const char*)(Kl + (i64)bc * IMG2) + h * 128;
  const char* bVT = (const char*)(Vh + (i64)bc * IMG2) + (i64)(h * 64) * 1024;

  union { u16x8 u; bf16x8 b; } one_u;
  #pragma unroll
  for (int k = 0; k < 8; ++k) one_u.u[k] = 0x3F80;
  const bf16x8 ones = one_u.b;

  int srow = tid >> 3, scolb = (tid & 7) * 16;
  int qtA = (blockIdx.x == 0) ? 3 : 2;

  #pragma unroll
  for (int seg = 0; seg < 2; ++seg) {
    int qt = seg == 0 ? qtA : 3 - qtA;
    const char* bQh = pQh + (i64)(qt * 128) * 1024;
    const char* bQl = pQl + (i64)(qt * 128) * 1024;

    bf16x8 qh[2][2], ql[2][2];
    #pragma unroll
    for (int qf = 0; qf < 2; ++qf)
      #pragma unroll
      for (int ks = 0; ks < 2; ++ks) {
        i64 off = (i64)(wid * 32 + qf * 16 + fr) * 1024 + ks * 64 + fg * 16;
        qh[qf][ks] = *(const bf16x8*)(bQh + off);
        ql[qf][ks] = *(const bf16x8*)(bQl + off);
      }

    float m_i[2][4], l_i[2][4];
    f32x4 acc[2][4] = {};
    #pragma unroll
    for (int qf = 0; qf < 2; ++qf)
      #pragma unroll
      for (int q = 0; q < 4; ++q) { m_i[qf][q] = -3e38f; l_i[qf][q] = 0.f; }

    int nst = 2 * qt + 2;

    __syncthreads();
    #pragma unroll
    for (int i = 0; i < 2; ++i) {
      int rr = i * 32 + srow;
      int cc = scolb ^ ((rr & 7) << 4);
      char* base = lds + i * 4096 + wid * 1024;
      gload_lds16(bKh + (i64)rr * 1024 + cc, base);
      gload_lds16(bKl + (i64)rr * 1024 + cc, base + 8192);
      gload_lds16(bVT + (i64)rr * 1024 + cc, base + 16384);
    }

    for (int st = 0; st < nst; ++st) {
      __syncthreads();
      if (st + 1 < nst) {
        int b = (st + 1) & 1;
        #pragma unroll
        for (int i = 0; i < 2; ++i) {
          int rr = i * 32 + srow;
          int cc = scolb ^ ((rr & 7) << 4);
          char* base = lds + b * 24576 + i * 4096 + wid * 1024;
          gload_lds16(bKh + (i64)((st + 1) * 64 + rr) * 1024 + cc, base);
          gload_lds16(bKl + (i64)((st + 1) * 64 + rr) * 1024 + cc, base + 8192);
          gload_lds16(bVT + (i64)rr * 1024 + (st + 1) * 128 + cc, base + 16384);
        }
      }
      const char* B = lds + (st & 1) * 24576;

      f32x4 sv[2][4] = {};
      __builtin_amdgcn_s_setprio(1);
      #pragma unroll
      for (int ks = 0; ks < 2; ++ks) {
        int ko = (ks * 64 + fg * 16) ^ swz;
        #pragma unroll
        for (int f = 0; f < 4; ++f) {
          bf16x8 bH = *(const bf16x8*)(B + (f * 16 + fr) * 128 + ko);
          bf16x8 bL = *(const bf16x8*)(B + 8192 + (f * 16 + fr) * 128 + ko);
          #pragma unroll
          for (int qf = 0; qf < 2; ++qf) {
            sv[qf][f] = __builtin_amdgcn_mfma_f32_16x16x32_bf16(qh[qf][ks], bH, sv[qf][f], 0, 0, 0);
            sv[qf][f] = __builtin_amdgcn_mfma_f32_16x16x32_bf16(qh[qf][ks], bL, sv[qf][f], 0, 0, 0);
            sv[qf][f] = __builtin_amdgcn_mfma_f32_16x16x32_bf16(ql[qf][ks], bH, sv[qf][f], 0, 0, 0);
          }
        }
      }
      __builtin_amdgcn_s_setprio(0);

      #pragma unroll
      for (int qf = 0; qf < 2; ++qf)
        #pragma unroll
        for (int f = 0; f < 4; ++f)
          #pragma unroll
          for (int q = 0; q < 4; ++q) {
            float x = sv[qf][f][q] * 0.125f;
            if (st >= 2 * qt) {
              int gq = qt * 128 + wid * 32 + qf * 16 + fg * 4 + q;
              int gk = st * 64 + f * 16 + fr;
              if (gk > gq) x = -3e38f;
            }
            sv[qf][f][q] = x;
          }

      float rm[2][4];
      #pragma unroll
      for (int qf = 0; qf < 2; ++qf)
        #pragma unroll
        for (int q = 0; q < 4; ++q)
          rm[qf][q] = fmaxf(fmaxf(sv[qf][0][q], sv[qf][1][q]), fmaxf(sv[qf][2][q], sv[qf][3][q]));
      #pragma unroll
      for (int off = 8; off >= 1; off >>= 1)
        #pragma unroll
        for (int qf = 0; qf < 2; ++qf)
          #pragma unroll
          for (int q = 0; q < 4; ++q)
            rm[qf][q] = fmaxf(rm[qf][q], __shfl_xor(rm[qf][q], off));

      float alpha[2][4];
      float pv[2][4][4];
      #pragma unroll
      for (int qf = 0; qf < 2; ++qf)
        #pragma unroll
        for (int q = 0; q < 4; ++q) {
          float mn = fmaxf(m_i[qf][q], rm[qf][q]);
          alpha[qf][q] = __expf(m_i[qf][q] - mn);
          m_i[qf][q] = mn;
          #pragma unroll
          for (int f = 0; f < 4; ++f)
            pv[qf][f][q] = __expf(sv[qf][f][q] - mn);
        }
      #pragma unroll
      for (int qf = 0; qf < 2; ++qf)
        #pragma unroll
        for (int q = 0; q < 4; ++q)
          #pragma unroll
          for (int fd = 0; fd < 4; ++fd)
            acc[qf][fd][q] *= alpha[qf][q];

      #pragma unroll
      for (int qf = 0; qf < 2; ++qf)
        #pragma unroll
        for (int f = 0; f < 4; ++f)
          #pragma unroll
          for (int q = 0; q < 4; ++q) {
            int tl = wid * 32 + qf * 16 + fg * 4 + q;
            *(ushort*)(lds + 49152 + tl * 128 + ((f * 32 + fr * 2) ^ ((tl & 7) << 4))) =
                f32_to_bf16_rtn(pv[qf][f][q]);
          }

      f32x4 accS[2] = {};
      __builtin_amdgcn_s_setprio(1);
      #pragma unroll
      for (int ks = 0; ks < 2; ++ks) {
        int ko = (ks * 64 + fg * 16) ^ swz;
        bf16x8 pa[2];
        #pragma unroll
        for (int qf = 0; qf < 2; ++qf)
          pa[qf] = *(const bf16x8*)(lds + 49152 + (wid * 32 + qf * 16 + fr) * 128 + ko);
        #pragma unroll
        for (int fd = 0; fd < 4; ++fd) {
          bf16x8 vh = *(const bf16x8*)(B + 16384 + (fd * 16 + fr) * 128 + ko);
          #pragma unroll
          for (int qf = 0; qf < 2; ++qf)
            acc[qf][fd] = __builtin_amdgcn_mfma_f32_16x16x32_bf16(pa[qf], vh, acc[qf][fd], 0, 0, 0);
        }
        #pragma unroll
        for (int qf = 0; qf < 2; ++qf)
          accS[qf] = __builtin_amdgcn_mfma_f32_16x16x32_bf16(pa[qf], ones, accS[qf], 0, 0, 0);
      }
      __builtin_amdgcn_s_setprio(0);

      #pragma unroll
      for (int qf = 0; qf < 2; ++qf)
        #pragma unroll
        for (int q = 0; q < 4; ++q)
          l_i[qf][q] = l_i[qf][q] * alpha[qf][q] + accS[qf][q];
    }

    #pragma unroll
    for (int qf = 0; qf < 2; ++qf)
      #pragma unroll
      for (int q = 0; q < 4; ++q) {
        float inv = 1.f / l_i[qf][q];
        int t = qt * 128 + wid * 32 + qf * 16 + fg * 4 + q;
        #pragma unroll
        for (int fd = 0; fd < 4; ++fd)
          out[((i64)bc * FULL + t) * FULL + h * 64 + fd * 16 + fr] = acc[qf][fd][q] * inv;
      }
  }
}

// ---------------------------------------------------------------- launch
extern "C" void kernel_launch(void* const* d_in, const int* in_sizes, int n_in,
                              void* d_out, int out_size, void* d_ws, size_t ws_size,
                              hipStream_t stream) {
  const float* idx_i  = (const float*)d_in[0];
  const float* idx_t  = (const float*)d_in[1];
  const float* idx_ir = (const float*)d_in[2];
  const float* Wli = (const float*)d_in[3];
  const float* bli = (const float*)d_in[4];
  const float* Wlt = (const float*)d_in[5];
  const float* blt = (const float*)d_in[6];
  const float* Wlir = (const float*)d_in[7];
  const float* blir = (const float*)d_in[8];
  const float* Wlo = (const float*)d_in[9];
  const float* blo = (const float*)d_in[10];
  const float* Wp  = (const float*)d_in[11];
  const float* bp  = (const float*)d_in[12];
  const float* Wk  = (const float*)d_in[13];
  const float* bk  = (const float*)d_in[14];
  const float* Wpi = (const float*)d_in[15];
  const float* bpi = (const float*)d_in[16];
  const float* Wki = (const float*)d_in[17];
  const float* bki = (const float*)d_in[18];
  const float* Wv  = (const float*)d_in[19];
  const float* bv  = (const float*)d_in[20];

  const i64 PL = (i64)NBC * FULL * FULL;
  const i64 WPL = (i64)FULL * FULL;
  const i64 AS = (i64)FULL * FULL;
  ushort* U = (ushort*)d_ws;
  ushort* s0 = U;            ushort* s1 = U + PL;
  ushort* s2 = U + 2 * PL;   ushort* s3 = U + 3 * PL;
  ushort* s4 = U + 4 * PL;   ushort* s5 = U + 5 * PL;
  ushort* s6 = U + 6 * PL;   ushort* s7 = U + 7 * PL;
  ushort* wreg = U + 8 * PL;
  float* Mbuf = (float*)(wreg + 16 * WPL);
  float* bias2 = Mbuf + (i64)192 * 4096;
  float* bpN = bias2 + (i64)NBC * FULL;
  float* bvN = bpN + 512;
  ushort* D0 = (ushort*)d_out;
  ushort* D1 = D0 + PL;
  float* keyF = (float*)s4;

  dim3 blk(256);
  dim3 blk512(512);

  auto mk = [](const ushort* Ah, const ushort* Al, const ushort* Bh, const ushort* Bl,
               const float* bias, i64 biasStride,
               float* Cf, ushort* Chi, ushort* Clo,
               i64 aStride, i64 bStride, i64 cStride, int bMod, int transC, int split3) {
    GDesc d; d.Ah = Ah; d.Al = Al; d.Bh = Bh; d.Bl = Bl; d.bias = bias;
    d.biasStride = biasStride; d.Cf = Cf; d.Chi = Chi; d.Clo = Clo;
    d.aStride = aStride; d.bStride = bStride; d.cStride = cStride;
    d.bMod = bMod; d.transC = transC; d.split3 = split3;
    return d;
  };

  // ---- fused preprocessing ----
  prep_all<<<2576, blk, 0, stream>>>(Wli, Wlt, Wlir, Wlo, Wk, Wki, Wp, Wv,
                                     blo, bp, bv,
                                     (const float4*)idx_i, (const float4*)idx_t,
                                     (const float4*)idx_ir,
                                     wreg, bpN, bvN,
                                     (ushort4*)s0, (ushort4*)s1,
                                     (ushort4*)s2, (ushort4*)s3,
                                     (ushort4*)s4, (ushort4*)s5, (int)(PL / 4));

  // G1: xt = idx_t@Wlt -> (6,7) | xir = idx_ir@Wlir -> (D0,D1)
  gemm_m<<<dim3(2, 2, 48), blk512, 0, stream>>>(
      mk(s2, s3, wreg + 2 * WPL, wreg + 3 * WPL, blt, 0, nullptr, s6, s7, AS, 0, AS, 1, 0, 1),
      mk(s4, s5, wreg + 4 * WPL, wreg + 5 * WPL, blir, 0, nullptr, D0, D1, AS, 0, AS, 1, 0, 1), 24);
  // G2: xi = x@Wli -> (2,3) | key = xt@Wk -> fp32 (4,5)
  gemm_m<<<dim3(2, 2, 48), blk512, 0, stream>>>(
      mk(s0, s1, wreg + 0 * WPL, wreg + 1 * WPL, bli, 0, nullptr, s2, s3, AS, 0, AS, 1, 0, 1),
      mk(s6, s7, wreg + 8 * WPL, wreg + 9 * WPL, bk, 0, keyF, nullptr, nullptr, AS, 0, AS, 1, 0, 1), 24);
  // mh + fused bias2 + transposeIP(xt in 6,7)
  mhfuse<<<192 + 48 * 36, blk, 0, stream>>>(keyF, Wpi, Mbuf, bpN, bpi, bias2, s6, s7);
  // G3: t1 = xi@xtT -> (4,5) | keyi = xir@Wki -> (0,1)
  gemm_m<<<dim3(2, 2, 48), blk512, 0, stream>>>(
      mk(s2, s3, s6, s7, nullptr, 0, nullptr, s4, s5, AS, AS, AS, NBC, 0, 1),
      mk(D0, D1, wreg + 10 * WPL, wreg + 11 * WPL, bki, 0, nullptr, s0, s1, AS, 0, AS, 1, 0, 1), 24);
  // xir -> xirT in place (D0,D1)
  transposeIP<<<dim3(8, 8, 48), blk, 0, stream>>>(D0, D1, AS);
  // G4: t2 = t1@xirT -> (2,3)
  {
    GDesc dt2 = mk(s4, s5, D0, D1, nullptr, 0, nullptr, s2, s3, AS, AS, AS, NBC, 0, 1);
    gemm_m<<<dim3(2, 2, 24), blk512, 0, stream>>>(dt2, dt2, 24);
  }
  // WpmT = 0.125 * (LWp @ M)^T -> (D0,D1)
  wpm_kernel<<<dim3(4, 192), blk, 0, stream>>>(Mbuf, wreg + 12 * WPL, wreg + 13 * WPL, D0, D1);
  // G6: q2 = t2@WpmT + bias2 -> (4,5) | valT = t2@LWvT + bvN (hi, transposed) -> (6)
  gemm_m<<<dim3(2, 2, 48), blk512, 0, stream>>>(
      mk(s2, s3, D0, D1, bias2, 512, nullptr, s4, s5, AS, AS, AS, NBC, 0, 1),
      mk(s2, s3, wreg + 14 * WPL, wreg + 15 * WPL, bvN, 0, nullptr, s6, nullptr, AS, 0, AS, 1, 1, 0), 24);
  // attention: Q(4,5), K(0,1), V^T(6) -> d_out
  attn5_kernel<<<dim3(2, 192), blk, 0, stream>>>(s4, s5, s0, s1, s6, (float*)d_out);
}

// Round 15
// 345.057 us; speedup vs baseline: 1.1727x; 1.1727x over previous
//
#include <hip/hip_runtime.h>

typedef long long i64;
typedef __attribute__((ext_vector_type(4))) float f32x4;
typedef __attribute__((ext_vector_type(8))) __bf16 bf16x8;
typedef __attribute__((ext_vector_type(8))) ushort u16x8;

#define FULL 512
#define NBC  24   // B*C = 8*3

__device__ __forceinline__ void gload_lds16(const void* g, void* l) {
  __builtin_amdgcn_global_load_lds(
      (const __attribute__((address_space(1))) void*)g,
      (__attribute__((address_space(3))) void*)l, 16, 0, 0);
}

__device__ __forceinline__ ushort f32_to_bf16_rtn(float x) {
  unsigned u = __float_as_uint(x);
  return (ushort)((u + 0x7FFFu + ((u >> 16) & 1u)) >> 16);
}

// ---------------------------------------------------------------- prep_all: fused preprocessing
__global__ __launch_bounds__(256) void prep_all(
    const float* __restrict__ Wli, const float* __restrict__ Wlt,
    const float* __restrict__ Wlir, const float* __restrict__ Wlo,
    const float* __restrict__ Wk, const float* __restrict__ Wki,
    const float* __restrict__ Wp, const float* __restrict__ Wv,
    const float* __restrict__ blo, const float* __restrict__ bp, const float* __restrict__ bv,
    const float4* __restrict__ ia, const float4* __restrict__ ib, const float4* __restrict__ ic,
    ushort* __restrict__ wreg, float* __restrict__ bpN, float* __restrict__ bvN,
    ushort4* __restrict__ xh, ushort4* __restrict__ xl,
    ushort4* __restrict__ th, ushort4* __restrict__ tl,
    ushort4* __restrict__ rh, ushort4* __restrict__ rl, int n4) {
  __shared__ __align__(16) char smem[34048];
  const i64 WPL = 262144;
  int id = blockIdx.x, tid = threadIdx.x;

  if (id < 384) {
    const float* I; ushort* outH; int inLD, r0, c0;
    if (id < 256) {
      int w = id >> 6, b6 = id & 63;
      r0 = (b6 >> 3) * 64; c0 = (b6 & 7) * 64; inLD = 512;
      const float* ins[4] = {Wli, Wlt, Wlir, Wlo};
      I = ins[w];
      outH = wreg + (i64)(2 * w) * WPL;
    } else {
      int q = id - 256;
      int z = q >> 3, y = q & 7;
      int w = z >> 3, b = z & 7;
      r0 = y * 64; c0 = 0; inLD = 64;
      I = (w ? Wki : Wk) + (i64)b * 512 * 64;
      outH = wreg + (i64)(2 * (4 + w)) * WPL + (i64)b * 64 * 512;
    }
    ushort* outL = outH + WPL;
    ushort (*sH)[68] = (ushort(*)[68])smem;
    ushort (*sL)[68] = (ushort(*)[68])(smem + 64 * 68 * 2);
    int tx = tid & 15, ty = tid >> 4;
    #pragma unroll
    for (int it = 0; it < 4; ++it) {
      int r = it * 16 + ty;
      float4 v = *(const float4*)&I[(i64)(r0 + r) * inLD + c0 + tx * 4];
      float vs[4] = {v.x, v.y, v.z, v.w};
      #pragma unroll
      for (int k = 0; k < 4; ++k) {
        ushort hh = f32_to_bf16_rtn(vs[k]);
        sH[tx * 4 + k][r] = hh;
        sL[tx * 4 + k][r] = f32_to_bf16_rtn(vs[k] - __uint_as_float((unsigned)hh << 16));
      }
    }
    __syncthreads();
    #pragma unroll
    for (int it = 0; it < 4; ++it) {
      int c = it * 16 + ty;
      ushort4 hv, lv;
      ushort* hp = (ushort*)&hv; ushort* lp = (ushort*)&lv;
      #pragma unroll
      for (int k = 0; k < 4; ++k) { hp[k] = sH[c][tx * 4 + k]; lp[k] = sL[c][tx * 4 + k]; }
      i64 off = (i64)(c0 + c) * 512 + r0 + tx * 4;
      *(ushort4*)&outH[off] = hv;
      *(ushort4*)&outL[off] = lv;
    }
  } else if (id < 512) {
    int q = id - 384;
    int sel = q >> 6, b6 = q & 63;
    const float* Wf = sel ? Wv : Wp;
    ushort* oH = wreg + (i64)(12 + 2 * sel) * WPL;
    ushort* oL = oH + WPL;
    int n0 = (b6 >> 3) * 64, k0 = (b6 & 7) * 64;
    int h = n0 >> 6;
    float (*sL)[65] = (float(*)[65])smem;
    float (*sF)[68] = (float(*)[68])(smem + 64 * 65 * 4);
    int tx = tid & 15, ty = tid >> 4;
    float acc[4][4] = {};
    for (int c0 = 0; c0 < 512; c0 += 64) {
      __syncthreads();
      #pragma unroll
      for (int it = 0; it < 4; ++it) {
        int idx = tid + it * 256;
        int r = idx >> 4, c4 = idx & 15;
        float4 v = *(const float4*)&Wlo[(i64)(k0 + r) * 512 + c0 + c4 * 4];
        sL[c4 * 4 + 0][r] = v.x; sL[c4 * 4 + 1][r] = v.y;
        sL[c4 * 4 + 2][r] = v.z; sL[c4 * 4 + 3][r] = v.w;
        float4 w = *(const float4*)&Wf[(i64)h * 32768 + (i64)(c0 + r) * 64 + c4 * 4];
        *(float4*)&sF[r][c4 * 4] = w;
      }
      __syncthreads();
      for (int c = 0; c < 64; ++c) {
        float fv[4], lv[4];
        #pragma unroll
        for (int i = 0; i < 4; ++i) fv[i] = sF[c][ty * 4 + i];
        #pragma unroll
        for (int j = 0; j < 4; ++j) lv[j] = sL[c][tx * 4 + j];
        #pragma unroll
        for (int i = 0; i < 4; ++i)
          #pragma unroll
          for (int j = 0; j < 4; ++j)
            acc[i][j] += fv[i] * lv[j];
      }
    }
    #pragma unroll
    for (int i = 0; i < 4; ++i)
      #pragma unroll
      for (int j = 0; j < 4; ++j) {
        float v = acc[i][j];
        i64 o = (i64)(n0 + ty * 4 + i) * 512 + k0 + tx * 4 + j;
        ushort hh = f32_to_bf16_rtn(v);
        oH[o] = hh;
        oL[o] = f32_to_bf16_rtn(v - __uint_as_float((unsigned)hh << 16));
      }
  } else if (id < 528) {
    int bidx = id - 512;
    int sel = bidx >> 3, h = bidx & 7;
    const float* W = sel ? Wv : Wp;
    int e = tid & 63, cq = tid >> 6;
    float s = 0.f;
    #pragma unroll 4
    for (int ci = 0; ci < 128; ++ci) {
      int c = cq * 128 + ci;
      s += blo[c] * W[(i64)h * 32768 + (i64)c * 64 + e];
    }
    float* red = (float*)smem;
    red[tid] = s;
    __syncthreads();
    if (cq == 0) {
      float v = red[e] + red[64 + e] + red[128 + e] + red[192 + e];
      int m = h * 64 + e;
      if (!sel) bpN[m] = v + bp[m];
      else      bvN[m] = v + bv[m];
    }
  } else {
    int i = (id - 528) * 256 + tid;
    int stride = 2048 * 256;
    for (; i < n4; i += stride) {
      float4 va = ia[i], vb = ib[i], vc = ic[i];
      float xs[4] = {va.x + vb.x + vc.x, va.y + vb.y + vc.y,
                     va.z + vb.z + vc.z, va.w + vb.w + vc.w};
      float bs[4] = {vb.x, vb.y, vb.z, vb.w};
      float cs[4] = {vc.x, vc.y, vc.z, vc.w};
      ushort4 h4, l4;
      ushort* hp = (ushort*)&h4; ushort* lp = (ushort*)&l4;
      #pragma unroll
      for (int k = 0; k < 4; ++k) {
        ushort hh = f32_to_bf16_rtn(xs[k]); hp[k] = hh;
        lp[k] = f32_to_bf16_rtn(xs[k] - __uint_as_float((unsigned)hh << 16));
      }
      xh[i] = h4; xl[i] = l4;
      #pragma unroll
      for (int k = 0; k < 4; ++k) {
        ushort hh = f32_to_bf16_rtn(bs[k]); hp[k] = hh;
        lp[k] = f32_to_bf16_rtn(bs[k] - __uint_as_float((unsigned)hh << 16));
      }
      th[i] = h4; tl[i] = l4;
      #pragma unroll
      for (int k = 0; k < 4; ++k) {
        ushort hh = f32_to_bf16_rtn(cs[k]); hp[k] = hh;
        lp[k] = f32_to_bf16_rtn(cs[k] - __uint_as_float((unsigned)hh << 16));
      }
      rh[i] = h4; rl[i] = l4;
    }
  }
}

// ---------------------------------------------------------------- in-place bf16 transpose
__global__ __launch_bounds__(256) void transposeIP(ushort* __restrict__ hi, ushort* __restrict__ lo,
                                                   i64 batch) {
  int bi = blockIdx.x, bj = blockIdx.y;
  if (bi > bj) return;
  int z = blockIdx.z;
  ushort* buf = ((z & 1) ? lo : hi) + (i64)(z >> 1) * batch;
  __shared__ ushort tA[64][68];
  __shared__ ushort tB[64][68];
  int tid = threadIdx.x, tx = tid & 15, ty = tid >> 4;
  #pragma unroll
  for (int it = 0; it < 4; ++it) {
    int r = it * 16 + ty;
    ushort4 a = *(const ushort4*)&buf[(i64)(bi * 64 + r) * 512 + bj * 64 + tx * 4];
    ushort* ap = (ushort*)&a;
    #pragma unroll
    for (int k = 0; k < 4; ++k) tA[tx * 4 + k][r] = ap[k];
    if (bi != bj) {
      ushort4 b = *(const ushort4*)&buf[(i64)(bj * 64 + r) * 512 + bi * 64 + tx * 4];
      ushort* bp = (ushort*)&b;
      #pragma unroll
      for (int k = 0; k < 4; ++k) tB[tx * 4 + k][r] = bp[k];
    }
  }
  __syncthreads();
  #pragma unroll
  for (int it = 0; it < 4; ++it) {
    int c = it * 16 + ty;
    ushort4 v; ushort* vp = (ushort*)&v;
    #pragma unroll
    for (int k = 0; k < 4; ++k) vp[k] = tA[c][tx * 4 + k];
    *(ushort4*)&buf[(i64)(bj * 64 + c) * 512 + bi * 64 + tx * 4] = v;
    if (bi != bj) {
      #pragma unroll
      for (int k = 0; k < 4; ++k) vp[k] = tB[c][tx * 4 + k];
      *(ushort4*)&buf[(i64)(bi * 64 + c) * 512 + bj * 64 + tx * 4] = v;
    }
  }
}

// ---------------------------------------------------------------- merged split-bf16 MFMA GEMM
// ROUND-13 PROVEN: 128^2 tile, all 4 planes via LDS (BK=32 dbuf, 64KB, 2 blocks/CU),
// one barrier/K-step, XCD-grouped remap, LDS-staged coalesced epilogue.
// NEW: heavy/light zz parity-interleave (ilv) so each XCD gets a mix of dA/dB sub-problems.
struct GDesc {
  const ushort *Ah, *Al, *Bh, *Bl;
  const float* bias;
  float* Cf; ushort* Chi; ushort* Clo;
  i64 aStride, bStride, cStride, biasStride;
  int bMod, transC, split3;
};

__global__ __launch_bounds__(256, 2) void gemm_m(GDesc dA, GDesc dB, int z0, int ilv) {
  int Zt = (int)gridDim.z;
  int hid = ((int)blockIdx.z * (int)gridDim.y + (int)blockIdx.y) * (int)gridDim.x + (int)blockIdx.x;
  int xcd = hid & 7, slot = hid >> 3;
  int G = xcd * (Zt >> 1) + (slot >> 2);
  int zzi = G >> 2;
  int zz = ilv ? ((zzi & 1) ? z0 + (zzi >> 1) : (zzi >> 1)) : zzi;
  int idx16 = (G & 3) * 4 + (slot & 3);
  int m0 = (idx16 >> 2) * 128, n0 = (idx16 & 3) * 128;

  GDesc d = (zz < z0) ? dA : dB;
  int z = (zz < z0) ? zz : zz - z0;
  const int K = 512, N = 512;
  const ushort* Ah = d.Ah + (i64)z * d.aStride + (i64)m0 * K;
  const ushort* Al = d.Al + (i64)z * d.aStride + (i64)m0 * K;
  const ushort* Bh = d.Bh + (i64)(z % d.bMod) * d.bStride + (i64)n0 * K;
  const ushort* Bl = d.Bl + (i64)(z % d.bMod) * d.bStride + (i64)n0 * K;

  __shared__ ushort lds[2 * 4 * 128 * 32];

  int tid = threadIdx.x;
  int lane = tid & 63, wid = tid >> 6;
  int wr = wid >> 1, wc = wid & 1;
  int fr = lane & 15, fg = lane >> 4;

  f32x4 acc[4][4] = {};

  auto STAGE = [&](int t, int b) {
    #pragma unroll
    for (int p = 0; p < 4; ++p) {
      if (!d.split3 && (p == 1 || p == 3)) continue;
      const ushort* gb = (p == 0) ? Ah : (p == 1) ? Al : (p == 2) ? Bh : Bl;
      #pragma unroll
      for (int it = 0; it < 2; ++it) {
        int pos = it * 4096 + tid * 16;
        int r = pos >> 6;
        int cb = (pos & 63) >> 4;
        int gcb = cb ^ ((r >> 1) & 3);
        const char* g = (const char*)gb + (i64)r * (K * 2) + t * 64 + gcb * 16;
        char* l = (char*)lds + b * 32768 + p * 8192 + it * 4096 + tid * 16;
        gload_lds16(g, l);
      }
    }
  };

  STAGE(0, 0);

  for (int t = 0; t < 16; ++t) {
    __syncthreads();
    if (t + 1 < 16) STAGE(t + 1, (t + 1) & 1);
    const char* B = (const char*)lds + (t & 1) * 32768;

    bf16x8 aH[4], aL[4], bH[4], bL[4];
    #pragma unroll
    for (int i = 0; i < 4; ++i) {
      int row = wr * 64 + i * 16 + fr;
      int off = row * 64 + ((fg ^ ((row >> 1) & 3)) << 4);
      aH[i] = *(const bf16x8*)(B + off);
      if (d.split3) aL[i] = *(const bf16x8*)(B + 8192 + off);
    }
    #pragma unroll
    for (int j = 0; j < 4; ++j) {
      int row = wc * 64 + j * 16 + fr;
      int off = row * 64 + ((fg ^ ((row >> 1) & 3)) << 4);
      bH[j] = *(const bf16x8*)(B + 16384 + off);
      if (d.split3) bL[j] = *(const bf16x8*)(B + 24576 + off);
    }
    if (d.split3) {
      #pragma unroll
      for (int i = 0; i < 4; ++i)
        #pragma unroll
        for (int j = 0; j < 4; ++j) {
          acc[i][j] = __builtin_amdgcn_mfma_f32_16x16x32_bf16(aH[i], bH[j], acc[i][j], 0, 0, 0);
          acc[i][j] = __builtin_amdgcn_mfma_f32_16x16x32_bf16(aH[i], bL[j], acc[i][j], 0, 0, 0);
          acc[i][j] = __builtin_amdgcn_mfma_f32_16x16x32_bf16(aL[i], bH[j], acc[i][j], 0, 0, 0);
        }
    } else {
      #pragma unroll
      for (int i = 0; i < 4; ++i)
        #pragma unroll
        for (int j = 0; j < 4; ++j)
          acc[i][j] = __builtin_amdgcn_mfma_f32_16x16x32_bf16(aH[i], bH[j], acc[i][j], 0, 0, 0);
    }
  }

  // ---------------- epilogue ----------------
  __syncthreads();
  char* wb = (char*)lds + wid * 16384;

  if (d.Cf) {
    int colBase = n0 + wc * 64 + fr;
    int rowBase = m0 + wr * 64 + fg * 4;
    #pragma unroll
    for (int j = 0; j < 4; ++j) {
      int col = colBase + j * 16;
      float bv = d.bias ? d.bias[(i64)z * d.biasStride + col] : 0.f;
      #pragma unroll
      for (int i = 0; i < 4; ++i)
        #pragma unroll
        for (int q = 0; q < 4; ++q)
          d.Cf[(i64)z * d.cStride + (i64)(rowBase + i * 16 + q) * N + col] = acc[i][j][q] + bv;
    }
  } else if (!d.transC) {
    #pragma unroll
    for (int j = 0; j < 4; ++j) {
      int coll = j * 16 + fr;
      float bv = d.bias ? d.bias[(i64)z * d.biasStride + n0 + wc * 64 + coll] : 0.f;
      #pragma unroll
      for (int i = 0; i < 4; ++i)
        #pragma unroll
        for (int q = 0; q < 4; ++q) {
          int rowl = i * 16 + fg * 4 + q;
          float v = acc[i][j][q] + bv;
          int off = rowl * 128 + ((((coll >> 3) ^ (rowl & 7)) << 4)) + (coll & 7) * 2;
          ushort hh = f32_to_bf16_rtn(v);
          *(ushort*)(wb + off) = hh;
          *(ushort*)(wb + 8192 + off) = f32_to_bf16_rtn(v - __uint_as_float((unsigned)hh << 16));
        }
    }
    #pragma unroll
    for (int rep = 0; rep < 8; ++rep) {
      int rowl = rep * 8 + (lane >> 3), chunk = lane & 7;
      int off = rowl * 128 + ((chunk ^ (rowl & 7)) << 4);
      u16x8 hv = *(const u16x8*)(wb + off);
      u16x8 lv = *(const u16x8*)(wb + 8192 + off);
      i64 gidx = (i64)z * d.cStride + (i64)(m0 + wr * 64 + rowl) * N + n0 + wc * 64 + chunk * 8;
      *(u16x8*)&d.Chi[gidx] = hv;
      *(u16x8*)&d.Clo[gidx] = lv;
    }
  } else {
    #pragma unroll
    for (int j = 0; j < 4; ++j) {
      int coll = j * 16 + fr;
      float bv = d.bias ? d.bias[(i64)z * d.biasStride + n0 + wc * 64 + coll] : 0.f;
      #pragma unroll
      for (int i = 0; i < 4; ++i)
        #pragma unroll
        for (int q = 0; q < 4; ++q) {
          int rowl = i * 16 + fg * 4 + q;
          float v = acc[i][j][q] + bv;
          int off = coll * 128 + ((((rowl >> 3) ^ (coll & 7)) << 4)) + (rowl & 7) * 2;
          *(ushort*)(wb + off) = f32_to_bf16_rtn(v);
        }
    }
    #pragma unroll
    for (int rep = 0; rep < 8; ++rep) {
      int colr = rep * 8 + (lane >> 3), chunk = lane & 7;
      int off = colr * 128 + ((chunk ^ (colr & 7)) << 4);
      u16x8 hv = *(const u16x8*)(wb + off);
      i64 gidx = (i64)z * d.cStride + (i64)(n0 + wc * 64 + colr) * N + m0 + wr * 64 + chunk * 8;
      *(u16x8*)&d.Chi[gidx] = hv;
    }
  }
}

// ---------------------------------------------------------------- mhfuse: mh + fused bias2 + transposeIP(xt)
__global__ __launch_bounds__(256) void mhfuse(
    const float* __restrict__ key, const float* __restrict__ Wpi, float* __restrict__ M,
    const float* __restrict__ bpN, const float* __restrict__ bpi, float* __restrict__ b2,
    ushort* __restrict__ xth, ushort* __restrict__ xtl) {
  __shared__ __align__(16) char smem[34816];
  int id = blockIdx.x, tid = threadIdx.x;

  if (id < 192) {
    float (*sK)[68] = (float(*)[68])smem;
    float (*sW)[68] = (float(*)[68])(smem + 17408);
    int z = id, bc = z >> 3, h = z & 7;
    const float* Kb = key + (i64)bc * FULL * FULL + h * 64;
    const float* Wb = Wpi + (i64)h * FULL * 64;
    float* Mb = M + (i64)z * 64 * 64;

    int tx = tid & 15, ty = tid >> 4;
    float acc[4][4] = {};

    for (int s0 = 0; s0 < FULL; s0 += 64) {
      __syncthreads();
      #pragma unroll
      for (int it = 0; it < 4; ++it) {
        int idx = tid + it * 256;
        int r = idx >> 4, c4 = idx & 15;
        *(float4*)&sK[r][c4 * 4] = *(const float4*)&Kb[(i64)(s0 + r) * FULL + c4 * 4];
        *(float4*)&sW[r][c4 * 4] = *(const float4*)&Wb[(i64)(s0 + r) * 64 + c4 * 4];
      }
      __syncthreads();
      for (int s = 0; s < 64; ++s) {
        float4 a4 = *(const float4*)&sK[s][ty * 4];
        float4 b4 = *(const float4*)&sW[s][tx * 4];
        float av[4] = {a4.x, a4.y, a4.z, a4.w};
        float bv[4] = {b4.x, b4.y, b4.z, b4.w};
        #pragma unroll
        for (int i = 0; i < 4; ++i)
          #pragma unroll
          for (int j = 0; j < 4; ++j)
            acc[i][j] += av[i] * bv[j];
      }
    }
    #pragma unroll
    for (int i = 0; i < 4; ++i)
      #pragma unroll
      for (int j = 0; j < 4; ++j)
        Mb[(ty * 4 + i) * 64 + tx * 4 + j] = acc[i][j];

    __syncthreads();
    float* red = (float*)smem;
    #pragma unroll
    for (int j = 0; j < 4; ++j) {
      float s = 0.f;
      #pragma unroll
      for (int i = 0; i < 4; ++i)
        s += bpN[h * 64 + ty * 4 + i] * acc[i][j];
      red[ty * 68 + tx * 4 + j] = s;
    }
    __syncthreads();
    if (tid < 64) {
      float s = 0.f;
      #pragma unroll
      for (int r = 0; r < 16; ++r) s += red[r * 68 + tid];
      b2[(i64)bc * 512 + h * 64 + tid] = 0.125f * s + bpi[h * 64 + tid];
    }
  } else {
    int id2 = id - 192;
    int z = id2 / 36, t = id2 % 36;
    int bi = 0;
    while (t >= 8 - bi) { t -= 8 - bi; ++bi; }
    int bj = bi + t;
    ushort* buf = ((z & 1) ? xtl : xth) + (i64)(z >> 1) * 262144;
    ushort (*tA)[68] = (ushort(*)[68])smem;
    ushort (*tB)[68] = (ushort(*)[68])(smem + 64 * 68 * 2);
    int tx = tid & 15, ty = tid >> 4;
    #pragma unroll
    for (int it = 0; it < 4; ++it) {
      int r = it * 16 + ty;
      ushort4 a = *(const ushort4*)&buf[(i64)(bi * 64 + r) * 512 + bj * 64 + tx * 4];
      ushort* ap = (ushort*)&a;
      #pragma unroll
      for (int k = 0; k < 4; ++k) tA[tx * 4 + k][r] = ap[k];
      if (bi != bj) {
        ushort4 b = *(const ushort4*)&buf[(i64)(bj * 64 + r) * 512 + bi * 64 + tx * 4];
        ushort* bp = (ushort*)&b;
        #pragma unroll
        for (int k = 0; k < 4; ++k) tB[tx * 4 + k][r] = bp[k];
      }
    }
    __syncthreads();
    #pragma unroll
    for (int it = 0; it < 4; ++it) {
      int c = it * 16 + ty;
      ushort4 v; ushort* vp = (ushort*)&v;
      #pragma unroll
      for (int k = 0; k < 4; ++k) vp[k] = tA[c][tx * 4 + k];
      *(ushort4*)&buf[(i64)(bj * 64 + c) * 512 + bi * 64 + tx * 4] = v;
      if (bi != bj) {
        #pragma unroll
        for (int k = 0; k < 4; ++k) vp[k] = tB[c][tx * 4 + k];
        *(ushort4*)&buf[(i64)(bi * 64 + c) * 512 + bj * 64 + tx * 4] = v;
      }
    }
  }
}

// ---------------------------------------------------------------- WpmT via LWpT planes
__global__ __launch_bounds__(256) void wpm_kernel(
    const float* __restrict__ M, const ushort* __restrict__ WpTh, const ushort* __restrict__ WpTl,
    ushort* __restrict__ outH, ushort* __restrict__ outL) {
  int z = blockIdx.y, h = z & 7;
  int s0 = blockIdx.x * 128;
  __shared__ float sM[64][65];
  __shared__ float sW[64][132];
  int tid = threadIdx.x;
  const float* Mb = M + (i64)z * 4096;
  for (int i = 0; i < 16; ++i) {
    int idx = i * 256 + tid;
    sM[idx >> 6][idx & 63] = Mb[idx];
  }
  for (int i = 0; i < 32; ++i) {
    int idx = i * 256 + tid;
    int e = idx >> 7, s = idx & 127;
    i64 g = (i64)(h * 64 + e) * 512 + s0 + s;
    sW[e][s] = __uint_as_float((unsigned)WpTh[g] << 16) +
               __uint_as_float((unsigned)WpTl[g] << 16);
  }
  __syncthreads();
  i64 obase = (i64)(z >> 3) * ((i64)FULL * FULL) + (i64)(h * 64) * 512 + s0;
  for (int i = 0; i < 32; ++i) {
    int idx = i * 256 + tid;
    int d = idx >> 7, s = idx & 127;
    float a = 0.f;
    #pragma unroll
    for (int e = 0; e < 64; ++e) a += sM[e][d] * sW[e][s];
    float v = 0.125f * a;
    i64 o = obase + (i64)d * 512 + s;
    ushort hh = f32_to_bf16_rtn(v);
    outH[o] = hh;
    outL[o] = f32_to_bf16_rtn(v - __uint_as_float((unsigned)hh << 16));
  }
}

// ---------------------------------------------------------------- MFMA flash attention v5 (r8 proven)
__global__ __launch_bounds__(256, 2) void attn5_kernel(
    const ushort* __restrict__ Qh, const ushort* __restrict__ Ql,
    const ushort* __restrict__ Kh, const ushort* __restrict__ Kl,
    const ushort* __restrict__ Vh, float* __restrict__ out) {
  int z = blockIdx.y;
  int bc = z >> 3, h = z & 7;
  __shared__ __align__(16) char lds[65536];
  int tid = threadIdx.x, lane = tid & 63, wid = tid >> 6;
  int fr = lane & 15, fg = lane >> 4;
  int swz = (fr & 7) << 4;

  const i64 IMG2 = 262144;
  const char* pQh = (const char*)(Qh + (i64)bc * IMG2) + h * 128;
  const char* pQl = (const char*)(Ql + (i64)bc * IMG2) + h * 128;
  const char* bKh = (const char*)(Kh + (i64)bc * IMG2) + h * 128;
  const char* bKl = (const char*)(Kl + (i64)bc * IMG2) + h * 128;
  const char* bVT = (const char*)(Vh + (i64)bc * IMG2) + (i64)(h * 64) * 1024;

  union { u16x8 u; bf16x8 b; } one_u;
  #pragma unroll
  for (int k = 0; k < 8; ++k) one_u.u[k] = 0x3F80;
  const bf16x8 ones = one_u.b;

  int srow = tid >> 3, scolb = (tid & 7) * 16;
  int qtA = (blockIdx.x == 0) ? 3 : 2;

  #pragma unroll
  for (int seg = 0; seg < 2; ++seg) {
    int qt = seg == 0 ? qtA : 3 - qtA;
    const char* bQh = pQh + (i64)(qt * 128) * 1024;
    const char* bQl = pQl + (i64)(qt * 128) * 1024;

    bf16x8 qh[2][2], ql[2][2];
    #pragma unroll
    for (int qf = 0; qf < 2; ++qf)
      #pragma unroll
      for (int ks = 0; ks < 2; ++ks) {
        i64 off = (i64)(wid * 32 + qf * 16 + fr) * 1024 + ks * 64 + fg * 16;
        qh[qf][ks] = *(const bf16x8*)(bQh + off);
        ql[qf][ks] = *(const bf16x8*)(bQl + off);
      }

    float m_i[2][4], l_i[2][4];
    f32x4 acc[2][4] = {};
    #pragma unroll
    for (int qf = 0; qf < 2; ++qf)
      #pragma unroll
      for (int q = 0; q < 4; ++q) { m_i[qf][q] = -3e38f; l_i[qf][q] = 0.f; }

    int nst = 2 * qt + 2;

    __syncthreads();
    #pragma unroll
    for (int i = 0; i < 2; ++i) {
      int rr = i * 32 + srow;
      int cc = scolb ^ ((rr & 7) << 4);
      char* base = lds + i * 4096 + wid * 1024;
      gload_lds16(bKh + (i64)rr * 1024 + cc, base);
      gload_lds16(bKl + (i64)rr * 1024 + cc, base + 8192);
      gload_lds16(bVT + (i64)rr * 1024 + cc, base + 16384);
    }

    for (int st = 0; st < nst; ++st) {
      __syncthreads();
      if (st + 1 < nst) {
        int b = (st + 1) & 1;
        #pragma unroll
        for (int i = 0; i < 2; ++i) {
          int rr = i * 32 + srow;
          int cc = scolb ^ ((rr & 7) << 4);
          char* base = lds + b * 24576 + i * 4096 + wid * 1024;
          gload_lds16(bKh + (i64)((st + 1) * 64 + rr) * 1024 + cc, base);
          gload_lds16(bKl + (i64)((st + 1) * 64 + rr) * 1024 + cc, base + 8192);
          gload_lds16(bVT + (i64)rr * 1024 + (st + 1) * 128 + cc, base + 16384);
        }
      }
      const char* B = lds + (st & 1) * 24576;

      f32x4 sv[2][4] = {};
      __builtin_amdgcn_s_setprio(1);
      #pragma unroll
      for (int ks = 0; ks < 2; ++ks) {
        int ko = (ks * 64 + fg * 16) ^ swz;
        #pragma unroll
        for (int f = 0; f < 4; ++f) {
          bf16x8 bH = *(const bf16x8*)(B + (f * 16 + fr) * 128 + ko);
          bf16x8 bL = *(const bf16x8*)(B + 8192 + (f * 16 + fr) * 128 + ko);
          #pragma unroll
          for (int qf = 0; qf < 2; ++qf) {
            sv[qf][f] = __builtin_amdgcn_mfma_f32_16x16x32_bf16(qh[qf][ks], bH, sv[qf][f], 0, 0, 0);
            sv[qf][f] = __builtin_amdgcn_mfma_f32_16x16x32_bf16(qh[qf][ks], bL, sv[qf][f], 0, 0, 0);
            sv[qf][f] = __builtin_amdgcn_mfma_f32_16x16x32_bf16(ql[qf][ks], bH, sv[qf][f], 0, 0, 0);
          }
        }
      }
      __builtin_amdgcn_s_setprio(0);

      #pragma unroll
      for (int qf = 0; qf < 2; ++qf)
        #pragma unroll
        for (int f = 0; f < 4; ++f)
          #pragma unroll
          for (int q = 0; q < 4; ++q) {
            float x = sv[qf][f][q] * 0.125f;
            if (st >= 2 * qt) {
              int gq = qt * 128 + wid * 32 + qf * 16 + fg * 4 + q;
              int gk = st * 64 + f * 16 + fr;
              if (gk > gq) x = -3e38f;
            }
            sv[qf][f][q] = x;
          }

      float rm[2][4];
      #pragma unroll
      for (int qf = 0; qf < 2; ++qf)
        #pragma unroll
        for (int q = 0; q < 4; ++q)
          rm[qf][q] = fmaxf(fmaxf(sv[qf][0][q], sv[qf][1][q]), fmaxf(sv[qf][2][q], sv[qf][3][q]));
      #pragma unroll
      for (int off = 8; off >= 1; off >>= 1)
        #pragma unroll
        for (int qf = 0; qf < 2; ++qf)
          #pragma unroll
          for (int q = 0; q < 4; ++q)
            rm[qf][q] = fmaxf(rm[qf][q], __shfl_xor(rm[qf][q], off));

      float alpha[2][4];
      float pv[2][4][4];
      #pragma unroll
      for (int qf = 0; qf < 2; ++qf)
        #pragma unroll
        for (int q = 0; q < 4; ++q) {
          float mn = fmaxf(m_i[qf][q], rm[qf][q]);
          alpha[qf][q] = __expf(m_i[qf][q] - mn);
          m_i[qf][q] = mn;
          #pragma unroll
          for (int f = 0; f < 4; ++f)
            pv[qf][f][q] = __expf(sv[qf][f][q] - mn);
        }
      #pragma unroll
      for (int qf = 0; qf < 2; ++qf)
        #pragma unroll
        for (int q = 0; q < 4; ++q)
          #pragma unroll
          for (int fd = 0; fd < 4; ++fd)
            acc[qf][fd][q] *= alpha[qf][q];

      #pragma unroll
      for (int qf = 0; qf < 2; ++qf)
        #pragma unroll
        for (int f = 0; f < 4; ++f)
          #pragma unroll
          for (int q = 0; q < 4; ++q) {
            int tl = wid * 32 + qf * 16 + fg * 4 + q;
            *(ushort*)(lds + 49152 + tl * 128 + ((f * 32 + fr * 2) ^ ((tl & 7) << 4))) =
                f32_to_bf16_rtn(pv[qf][f][q]);
          }

      f32x4 accS[2] = {};
      __builtin_amdgcn_s_setprio(1);
      #pragma unroll
      for (int ks = 0; ks < 2; ++ks) {
        int ko = (ks * 64 + fg * 16) ^ swz;
        bf16x8 pa[2];
        #pragma unroll
        for (int qf = 0; qf < 2; ++qf)
          pa[qf] = *(const bf16x8*)(lds + 49152 + (wid * 32 + qf * 16 + fr) * 128 + ko);
        #pragma unroll
        for (int fd = 0; fd < 4; ++fd) {
          bf16x8 vh = *(const bf16x8*)(B + 16384 + (fd * 16 + fr) * 128 + ko);
          #pragma unroll
          for (int qf = 0; qf < 2; ++qf)
            acc[qf][fd] = __builtin_amdgcn_mfma_f32_16x16x32_bf16(pa[qf], vh, acc[qf][fd], 0, 0, 0);
        }
        #pragma unroll
        for (int qf = 0; qf < 2; ++qf)
          accS[qf] = __builtin_amdgcn_mfma_f32_16x16x32_bf16(pa[qf], ones, accS[qf], 0, 0, 0);
      }
      __builtin_amdgcn_s_setprio(0);

      #pragma unroll
      for (int qf = 0; qf < 2; ++qf)
        #pragma unroll
        for (int q = 0; q < 4; ++q)
          l_i[qf][q] = l_i[qf][q] * alpha[qf][q] + accS[qf][q];
    }

    #pragma unroll
    for (int qf = 0; qf < 2; ++qf)
      #pragma unroll
      for (int q = 0; q < 4; ++q) {
        float inv = 1.f / l_i[qf][q];
        int t = qt * 128 + wid * 32 + qf * 16 + fg * 4 + q;
        #pragma unroll
        for (int fd = 0; fd < 4; ++fd)
          out[((i64)bc * FULL + t) * FULL + h * 64 + fd * 16 + fr] = acc[qf][fd][q] * inv;
      }
  }
}

// ---------------------------------------------------------------- launch
extern "C" void kernel_launch(void* const* d_in, const int* in_sizes, int n_in,
                              void* d_out, int out_size, void* d_ws, size_t ws_size,
                              hipStream_t stream) {
  const float* idx_i  = (const float*)d_in[0];
  const float* idx_t  = (const float*)d_in[1];
  const float* idx_ir = (const float*)d_in[2];
  const float* Wli = (const float*)d_in[3];
  const float* bli = (const float*)d_in[4];
  const float* Wlt = (const float*)d_in[5];
  const float* blt = (const float*)d_in[6];
  const float* Wlir = (const float*)d_in[7];
  const float* blir = (const float*)d_in[8];
  const float* Wlo = (const float*)d_in[9];
  const float* blo = (const float*)d_in[10];
  const float* Wp  = (const float*)d_in[11];
  const float* bp  = (const float*)d_in[12];
  const float* Wk  = (const float*)d_in[13];
  const float* bk  = (const float*)d_in[14];
  const float* Wpi = (const float*)d_in[15];
  const float* bpi = (const float*)d_in[16];
  const float* Wki = (const float*)d_in[17];
  const float* bki = (const float*)d_in[18];
  const float* Wv  = (const float*)d_in[19];
  const float* bv  = (const float*)d_in[20];

  const i64 PL = (i64)NBC * FULL * FULL;
  const i64 WPL = (i64)FULL * FULL;
  const i64 AS = (i64)FULL * FULL;
  ushort* U = (ushort*)d_ws;
  ushort* s0 = U;            ushort* s1 = U + PL;
  ushort* s2 = U + 2 * PL;   ushort* s3 = U + 3 * PL;
  ushort* s4 = U + 4 * PL;   ushort* s5 = U + 5 * PL;
  ushort* s6 = U + 6 * PL;   ushort* s7 = U + 7 * PL;
  ushort* wreg = U + 8 * PL;
  float* Mbuf = (float*)(wreg + 16 * WPL);
  float* bias2 = Mbuf + (i64)192 * 4096;
  float* bpN = bias2 + (i64)NBC * FULL;
  float* bvN = bpN + 512;
  ushort* D0 = (ushort*)d_out;
  ushort* D1 = D0 + PL;
  float* keyF = (float*)s4;

  dim3 blk(256);

  auto mk = [](const ushort* Ah, const ushort* Al, const ushort* Bh, const ushort* Bl,
               const float* bias, i64 biasStride,
               float* Cf, ushort* Chi, ushort* Clo,
               i64 aStride, i64 bStride, i64 cStride, int bMod, int transC, int split3) {
    GDesc d; d.Ah = Ah; d.Al = Al; d.Bh = Bh; d.Bl = Bl; d.bias = bias;
    d.biasStride = biasStride; d.Cf = Cf; d.Chi = Chi; d.Clo = Clo;
    d.aStride = aStride; d.bStride = bStride; d.cStride = cStride;
    d.bMod = bMod; d.transC = transC; d.split3 = split3;
    return d;
  };

  // ---- fused preprocessing ----
  prep_all<<<2576, blk, 0, stream>>>(Wli, Wlt, Wlir, Wlo, Wk, Wki, Wp, Wv,
                                     blo, bp, bv,
                                     (const float4*)idx_i, (const float4*)idx_t,
                                     (const float4*)idx_ir,
                                     wreg, bpN, bvN,
                                     (ushort4*)s0, (ushort4*)s1,
                                     (ushort4*)s2, (ushort4*)s3,
                                     (ushort4*)s4, (ushort4*)s5, (int)(PL / 4));

  // G1: xt = idx_t@Wlt -> (6,7) | xir = idx_ir@Wlir -> (D0,D1)
  gemm_m<<<dim3(4, 4, 48), blk, 0, stream>>>(
      mk(s2, s3, wreg + 2 * WPL, wreg + 3 * WPL, blt, 0, nullptr, s6, s7, AS, 0, AS, 1, 0, 1),
      mk(s4, s5, wreg + 4 * WPL, wreg + 5 * WPL, blir, 0, nullptr, D0, D1, AS, 0, AS, 1, 0, 1), 24, 1);
  // G2: xi = x@Wli -> (2,3) | key = xt@Wk -> fp32 (4,5)
  gemm_m<<<dim3(4, 4, 48), blk, 0, stream>>>(
      mk(s0, s1, wreg + 0 * WPL, wreg + 1 * WPL, bli, 0, nullptr, s2, s3, AS, 0, AS, 1, 0, 1),
      mk(s6, s7, wreg + 8 * WPL, wreg + 9 * WPL, bk, 0, keyF, nullptr, nullptr, AS, 0, AS, 1, 0, 1), 24, 1);
  // mh + fused bias2 + transposeIP(xt in 6,7)
  mhfuse<<<192 + 48 * 36, blk, 0, stream>>>(keyF, Wpi, Mbuf, bpN, bpi, bias2, s6, s7);
  // G3: t1 = xi@xtT -> (4,5) | keyi = xir@Wki -> (0,1)
  gemm_m<<<dim3(4, 4, 48), blk, 0, stream>>>(
      mk(s2, s3, s6, s7, nullptr, 0, nullptr, s4, s5, AS, AS, AS, NBC, 0, 1),
      mk(D0, D1, wreg + 10 * WPL, wreg + 11 * WPL, bki, 0, nullptr, s0, s1, AS, 0, AS, 1, 0, 1), 24, 1);
  // xir -> xirT in place (D0,D1)
  transposeIP<<<dim3(8, 8, 48), blk, 0, stream>>>(D0, D1, AS);
  // G4: t2 = t1@xirT -> (2,3)
  {
    GDesc dt2 = mk(s4, s5, D0, D1, nullptr, 0, nullptr, s2, s3, AS, AS, AS, NBC, 0, 1);
    gemm_m<<<dim3(4, 4, 24), blk, 0, stream>>>(dt2, dt2, 24, 0);
  }
  // WpmT = 0.125 * (LWp @ M)^T -> (D0,D1)
  wpm_kernel<<<dim3(4, 192), blk, 0, stream>>>(Mbuf, wreg + 12 * WPL, wreg + 13 * WPL, D0, D1);
  // G6: q2 = t2@WpmT + bias2 -> (4,5) | valT = t2@LWvT + bvN (hi, transposed) -> (6)
  gemm_m<<<dim3(4, 4, 48), blk, 0, stream>>>(
      mk(s2, s3, D0, D1, bias2, 512, nullptr, s4, s5, AS, AS, AS, NBC, 0, 1),
      mk(s2, s3, wreg + 14 * WPL, wreg + 15 * WPL, bvN, 0, nullptr, s6, nullptr, AS, 0, AS, 1, 1, 0), 24, 1);
  // attention: Q(4,5), K(0,1), V^T(6) -> d_out
  attn5_kernel<<<dim3(2, 192), blk, 0, stream>>>(s4, s5, s0, s1, s6, (float*)d_out);
}